// Round 9
// baseline (256.588 us; speedup 1.0000x reference)
//
#include <hip/hip_runtime.h>
#include <hip/hip_bf16.h>
#include <stdint.h>

typedef unsigned short u16;
typedef short short8 __attribute__((ext_vector_type(8)));
typedef short short4v __attribute__((ext_vector_type(4)));
typedef float floatx4 __attribute__((ext_vector_type(4)));

__device__ __forceinline__ float b2f(u16 v) {
  union { unsigned int u; float f; } c; c.u = ((unsigned int)v) << 16; return c.f;
}
__device__ __forceinline__ u16 f2b(float f) {
  union { float f; unsigned int u; } c; c.f = f;
  unsigned int u = c.u;
  return (u16)((u + 0x7fffu + ((u >> 16) & 1u)) >> 16);  // RNE
}

// async global->LDS, 16B per lane. LDS dest must be wave-uniform base + lane*16.
__device__ __forceinline__ void gld_lds16(const u16* g, u16* l) {
  __builtin_amdgcn_global_load_lds(
      (const __attribute__((address_space(1))) unsigned int*)g,
      (__attribute__((address_space(3))) unsigned int*)l,
      16, 0, 0);
}

// ---------------------------------------------------------------------------
// Fused prep: x fp32->bf16 (0..6143), w_attn T (6144..6575), w_proj T
// (6576..6719), out := bias broadcast (6720..12863; seeds the split-K proj).
// ---------------------------------------------------------------------------
__device__ __forceinline__ void tile_transpose_f2b(
    const float* __restrict__ in, u16* __restrict__ out,
    int inRS, int outRS, int rb, int cb, int tid)
{
  __shared__ __align__(16) u16 t[64][72];
  const int r = tid >> 2, sg = tid & 3;
  const float* ip = in + (long)(rb + r) * inRS + cb + sg * 16;
#pragma unroll
  for (int i = 0; i < 16; i += 4) {
    float4 f = *(const float4*)(ip + i);
    t[r][sg * 16 + i]     = f2b(f.x);
    t[r][sg * 16 + i + 1] = f2b(f.y);
    t[r][sg * 16 + i + 2] = f2b(f.z);
    t[r][sg * 16 + i + 3] = f2b(f.w);
  }
  __syncthreads();
  short8 v0, v1;
#pragma unroll
  for (int i = 0; i < 8; i++) v0[i] = (short)t[sg * 16 + i][r];
#pragma unroll
  for (int i = 0; i < 8; i++) v1[i] = (short)t[sg * 16 + 8 + i][r];
  *(short8*)(out + (long)(cb + r) * outRS + rb + sg * 16)     = v0;
  *(short8*)(out + (long)(cb + r) * outRS + rb + sg * 16 + 8) = v1;
}

__global__ __launch_bounds__(256) void prep(
    const float* __restrict__ x, u16* __restrict__ xb,
    const float* __restrict__ w_attn, u16* __restrict__ wTa,
    const float* __restrict__ w_proj, u16* __restrict__ wTp,
    const float* __restrict__ b_proj, float* __restrict__ out)
{
  const int bid = blockIdx.x, tid = threadIdx.x;
  if (bid < 6144) {
    int i = (bid * 256 + tid) * 4;
    float4 f = *(const float4*)(x + i);
    short4v v;
    v[0] = (short)f2b(f.x); v[1] = (short)f2b(f.y);
    v[2] = (short)f2b(f.z); v[3] = (short)f2b(f.w);
    *(short4v*)(xb + i) = v;
  } else if (bid < 6576) {
    int t = bid - 6144;                 // 36 x 12 tiles of w_attn [768][2304]
    tile_transpose_f2b(w_attn, wTa, 2304, 768, (t / 36) * 64, (t % 36) * 64, tid);
  } else if (bid < 6720) {
    int t = bid - 6576;                 // 12 x 12 tiles of w_proj [768][768]
    tile_transpose_f2b(w_proj, wTp, 768, 768, (t / 12) * 64, (t % 12) * 64, tid);
  } else {
    int i = ((bid - 6720) * 256 + tid) * 4;     // out := bias (fp32)
    *(float4*)(out + i) = *(const float4*)(b_proj + (i % 768));
  }
}

// ---------------------------------------------------------------------------
// C = A * Bt^T (+bias)  (A,Bt bf16, fp32 accum). R5 double-buffer K-loop
// (measured best; raw-vmcnt R6 and XCD swizzle R7 both regressed — frozen).
// MODE 0: dense store C+bias. MODE 1 (qkv): cols<1536 -> qk, V cols -> vT
// transposed. MODE 2 (proj split-K): blockIdx.z picks K-chunk, epilogue
// atomicAdd into pre-seeded C, no bias.
// ---------------------------------------------------------------------------
__device__ __forceinline__ void store_out(u16* p, float v)  { *p = f2b(v); }
__device__ __forceinline__ void store_out(float* p, float v) { *p = v; }

template <int BM>
__device__ __forceinline__ void stage(
    const u16* __restrict__ A, const u16* __restrict__ Bt,
    long rowbase, long colbase, int K, int k0,
    u16* dA, u16* dB, int tid)
{
  const int c0 = tid, c1 = tid + 256;
  const int ar0 = c0 >> 2, ak0 = (c0 & 3) * 8;
  const int ar1 = c1 >> 2, ak1 = (c1 & 3) * 8;
  gld_lds16(A + (rowbase + ar0) * K + k0 + ak0, dA + c0 * 8);
  if (BM == 128)
    gld_lds16(A + (rowbase + ar1) * K + k0 + ak1, dA + c1 * 8);
  gld_lds16(Bt + (colbase + ar0) * K + k0 + ak0, dB + c0 * 8);
  gld_lds16(Bt + (colbase + ar1) * K + k0 + ak1, dB + c1 * 8);
}

template <typename OT, int BM, int MODE>
__global__ __launch_bounds__(256) void gemm_bt_bias(
    const u16* __restrict__ A, const u16* __restrict__ Bt,
    const float* __restrict__ bias, OT* __restrict__ C, u16* __restrict__ vT,
    int M, int N, int K, int strideC)
{
  constexpr int WNF = (BM == 128) ? 4 : 2;      // n-frags per wave
  __shared__ __align__(16) u16 sA[2][BM * 32];
  __shared__ __align__(16) u16 sB[2][128 * 32];
  const int tid = threadIdx.x;
  const int lane = tid & 63;
  const int wave = tid >> 6;
  const int wm = (BM == 128) ? (wave >> 1) * 64 : 0;
  const int wn = (BM == 128) ? (wave & 1) * 64 : wave * 32;
  const int l15 = lane & 15;
  const int q = lane >> 4;
  const long rowbase = (long)blockIdx.y * BM;
  const long colbase = (long)blockIdx.x * 128;
  const int kchunk = (MODE == 2) ? K / gridDim.z : K;
  const int kbase  = (MODE == 2) ? blockIdx.z * kchunk : 0;

  floatx4 acc[4][WNF];
#pragma unroll
  for (int i = 0; i < 4; i++)
#pragma unroll
    for (int j = 0; j < WNF; j++) acc[i][j] = (floatx4){0.f, 0.f, 0.f, 0.f};

  stage<BM>(A, Bt, rowbase, colbase, K, kbase, sA[0], sB[0], tid);
  __syncthreads();   // buf0 ready

  const int NIT = kchunk / 32;
  for (int it = 0; it < NIT; ++it) {
    const int cur = it & 1;
    if (it + 1 < NIT)
      stage<BM>(A, Bt, rowbase, colbase, K, kbase + (it + 1) * 32, sA[cur ^ 1], sB[cur ^ 1], tid);
    short8 af[4], bf[WNF];
#pragma unroll
    for (int mt = 0; mt < 4; mt++)
      af[mt] = *(const short8*)(sA[cur] + (wm + mt * 16 + l15) * 32 + q * 8);
#pragma unroll
    for (int nt = 0; nt < WNF; nt++)
      bf[nt] = *(const short8*)(sB[cur] + (wn + nt * 16 + l15) * 32 + q * 8);
#pragma unroll
    for (int mt = 0; mt < 4; mt++)
#pragma unroll
      for (int nt = 0; nt < WNF; nt++)
        acc[mt][nt] = __builtin_amdgcn_mfma_f32_16x16x32_bf16(af[mt], bf[nt], acc[mt][nt], 0, 0, 0);
    if (it + 1 < NIT) __syncthreads();
  }

  if (MODE == 1 && colbase >= 1536) {
    // V region -> vT[b*12+h][d][t], packed 4-row (t-consecutive) stores
    const long b = rowbase >> 10;
    const int t0b = (int)(rowbase & 1023) + wm;
#pragma unroll
    for (int nt = 0; nt < WNF; nt++) {
      const int col = (int)colbase + wn + nt * 16 + l15;
      const float bv = bias[col];
      const int dloc = col - 1536;
      u16* bp = vT + (b * 12 + (dloc >> 6)) * 65536L + (long)(dloc & 63) * 1024;
#pragma unroll
      for (int mt = 0; mt < 4; mt++) {
        short4v pv;
#pragma unroll
        for (int r = 0; r < 4; r++) pv[r] = (short)f2b(acc[mt][nt][r] + bv);
        *(short4v*)(bp + t0b + mt * 16 + q * 4) = pv;
      }
    }
  } else if (MODE == 2) {
#pragma unroll
    for (int nt = 0; nt < WNF; nt++) {
      const long col = colbase + wn + nt * 16 + l15;
#pragma unroll
      for (int mt = 0; mt < 4; mt++)
#pragma unroll
        for (int r = 0; r < 4; r++) {
          const long row = rowbase + wm + mt * 16 + q * 4 + r;
          atomicAdd((float*)C + row * strideC + col, acc[mt][nt][r]);
        }
    }
  } else {
#pragma unroll
    for (int nt = 0; nt < WNF; nt++) {
      const long col = colbase + wn + nt * 16 + l15;
      const float bv = bias[col];
#pragma unroll
      for (int mt = 0; mt < 4; mt++)
#pragma unroll
        for (int r = 0; r < 4; r++) {
          const long row = rowbase + wm + mt * 16 + q * 4 + r;
          store_out(C + row * strideC + col, acc[mt][nt][r] + bv);
        }
    }
  }
}

// ---------------------------------------------------------------------------
// Flash attention, causal. One block = (b*12+h, q-tile of 64 rows), 256 thr.
// S^T = K (Q/8)^T: in-register online softmax. V pre-transposed (vT).
// Causal mask applied ONLY on the diagonal tile j==qt (j<qt is mask-free).
// ---------------------------------------------------------------------------
__global__ __launch_bounds__(256) void attn_fwd(
    const u16* __restrict__ qk, const u16* __restrict__ vT, u16* __restrict__ y)
{
  const int bh = blockIdx.x;        // b*12 + h
  const int qt = 15 - blockIdx.y;   // reversed: long blocks dispatch first
  const int b = bh / 12, h = bh % 12;
  const long rowOff = (long)b * 1024;
  const int qb = qt * 64;

  __shared__ __align__(16) u16 sK[64 * 72];
  __shared__ __align__(16) u16 sV[2][64 * 72];  // V^T [d][key], double-buffered
  __shared__ __align__(16) u16 sP[64 * 72];     // P [qrow][key]

  const int tid = threadIdx.x;
  const int lane = tid & 63, wave = tid >> 6;
  const int l15 = lane & 15, q = lane >> 4;
  const int qrow_g = qb + wave * 16 + l15;    // this lane's softmax row

  // Q fragments in registers, pre-scaled by 1/8 (B-operand: n=l15, k=q*8+j)
  short8 qf[2];
  {
    const u16* qp = qk + (long)(rowOff + qrow_g) * 1536 + h * 64 + q * 8;
    short8 a0 = *(const short8*)(qp);
    short8 a1 = *(const short8*)(qp + 32);
#pragma unroll
    for (int i = 0; i < 8; i++) {
      a0[i] = (short)f2b(b2f((u16)a0[i]) * 0.125f);
      a1[i] = (short)f2b(b2f((u16)a1[i]) * 0.125f);
    }
    qf[0] = a0; qf[1] = a1;
  }

  float m_i = -1e30f, l_i = 0.f;
  floatx4 o[4];
#pragma unroll
  for (int nt = 0; nt < 4; nt++) o[nt] = (floatx4){0.f, 0.f, 0.f, 0.f};

  for (int j = 0; j <= qt; j++) {
    const int jb = j * 64;
    u16* sVc = sV[j & 1];
#pragma unroll
    for (int rep = 0; rep < 2; rep++) {
      int idx = tid + rep * 256;
      int r = idx >> 3, ch = (idx & 7) * 8;
      *(short8*)(sK + r * 72 + ch) =
          *(const short8*)(qk + (long)(rowOff + jb + r) * 1536 + 768 + h * 64 + ch);
      *(short8*)(sVc + r * 72 + ch) =
          *(const short8*)(vT + (long)bh * 65536 + (long)r * 1024 + jb + ch);
    }
    __syncthreads();

    // S^T = K (Q/8)^T : fragments mt over 16-key blocks
    floatx4 sf[4];
#pragma unroll
    for (int mt = 0; mt < 4; mt++) sf[mt] = (floatx4){0.f, 0.f, 0.f, 0.f};
#pragma unroll
    for (int kk = 0; kk < 2; kk++) {
#pragma unroll
      for (int mt = 0; mt < 4; mt++) {
        short8 kf = *(const short8*)(sK + (mt * 16 + l15) * 72 + kk * 32 + q * 8);
        sf[mt] = __builtin_amdgcn_mfma_f32_16x16x32_bf16(kf, qf[kk], sf[mt], 0, 0, 0);
      }
    }

    // online softmax (row = l15-qrow); mask only the diagonal tile
    float mx = m_i;
    if (j == qt) {
#pragma unroll
      for (int mt = 0; mt < 4; mt++)
#pragma unroll
        for (int r = 0; r < 4; r++) {
          int key_g = jb + mt * 16 + q * 4 + r;
          float v = sf[mt][r];
          if (key_g > qrow_g) v = -1e30f;
          sf[mt][r] = v;
          mx = fmaxf(mx, v);
        }
    } else {
#pragma unroll
      for (int mt = 0; mt < 4; mt++)
#pragma unroll
        for (int r = 0; r < 4; r++) mx = fmaxf(mx, sf[mt][r]);
    }
    mx = fmaxf(mx, __shfl_xor(mx, 16));
    mx = fmaxf(mx, __shfl_xor(mx, 32));
    float al = __expf(m_i - mx);
    m_i = mx;
    float rsum = 0.f;
#pragma unroll
    for (int mt = 0; mt < 4; mt++) {
      short4v pv;
#pragma unroll
      for (int r = 0; r < 4; r++) {
        float p = __expf(sf[mt][r] - mx);
        rsum += p;
        pv[r] = (short)f2b(p);
      }
      *(short4v*)(sP + (wave * 16 + l15) * 72 + mt * 16 + q * 4) = pv;
    }
    rsum += __shfl_xor(rsum, 16);
    rsum += __shfl_xor(rsum, 32);
    l_i = l_i * al + rsum;
    __syncthreads();   // sP + this iter's sV visible before PV

    // O = O*alpha + P V
    float al_r[4];
#pragma unroll
    for (int r = 0; r < 4; r++) al_r[r] = __shfl(al, q * 4 + r);
#pragma unroll
    for (int nt = 0; nt < 4; nt++)
#pragma unroll
      for (int r = 0; r < 4; r++) o[nt][r] *= al_r[r];
#pragma unroll
    for (int kk = 0; kk < 2; kk++) {
      short8 pf = *(const short8*)(sP + (wave * 16 + l15) * 72 + kk * 32 + q * 8);
#pragma unroll
      for (int nt = 0; nt < 4; nt++) {
        short8 vf = *(const short8*)(sVc + (nt * 16 + l15) * 72 + kk * 32 + q * 8);
        o[nt] = __builtin_amdgcn_mfma_f32_16x16x32_bf16(pf, vf, o[nt], 0, 0, 0);
      }
    }
  }

  float linv = 1.f / l_i;
  float li_r[4];
#pragma unroll
  for (int r = 0; r < 4; r++) li_r[r] = __shfl(linv, q * 4 + r);
#pragma unroll
  for (int nt = 0; nt < 4; nt++)
#pragma unroll
    for (int r = 0; r < 4; r++) {
      int row = qb + wave * 16 + q * 4 + r;
      int col = h * 64 + nt * 16 + l15;
      y[(rowOff + row) * 768 + col] = f2b(o[nt][r] * li_r[r]);
    }
}

// ---------------------------------------------------------------------------
extern "C" void kernel_launch(void* const* d_in, const int* in_sizes, int n_in,
                              void* d_out, int out_size, void* d_ws, size_t ws_size,
                              hipStream_t stream) {
  const float* x      = (const float*)d_in[0];  // [8192][768] fp32
  const float* w_attn = (const float*)d_in[1];  // [768][2304] fp32
  const float* b_attn = (const float*)d_in[2];  // [2304] fp32
  const float* w_proj = (const float*)d_in[3];  // [768][768] fp32
  const float* b_proj = (const float*)d_in[4];  // [768] fp32
  float* out = (float*)d_out;                   // [8192][768] fp32

  char* ws = (char*)d_ws;
  u16* xb   = (u16*)ws; ws += (size_t)8192 * 768 * 2;     // 12.6 MB
  u16* wTa  = (u16*)ws; ws += (size_t)2304 * 768 * 2;     //  3.5 MB
  u16* wTp  = (u16*)ws; ws += (size_t)768 * 768 * 2;      //  1.2 MB
  u16* qk   = (u16*)ws; ws += (size_t)8192 * 1536 * 2;    // 25.2 MB (Q|K)
  u16* vT   = (u16*)ws; ws += (size_t)96 * 64 * 1024 * 2; // 12.6 MB (V^T)
  u16* yatt = (u16*)ws; ws += (size_t)8192 * 768 * 2;     // 12.6 MB

  // fused prep: x->bf16, weight transposes, out := bias (split-K seed)
  prep<<<dim3(12864), 256, 0, stream>>>(x, xb, w_attn, wTa, w_proj, wTp, b_proj, out);

  // qkv GEMM: Q|K -> qk (strided), V -> vT (transposed in epilogue)
  gemm_bt_bias<u16, 128, 1><<<dim3(18, 64), 256, 0, stream>>>(
      xb, wTa, b_attn, qk, vT, 8192, 2304, 768, 1536);

  // flash attention (V pre-transposed; in-register softmax; diag-only mask)
  attn_fwd<<<dim3(96, 16), 256, 0, stream>>>(qk, vT, yatt);

  // out += yatt @ w_proj   (split-K=3, atomic fp32; bias pre-seeded by prep)
  gemm_bt_bias<float, 64, 2><<<dim3(6, 128, 3), 256, 0, stream>>>(
      yatt, wTp, b_proj, out, (u16*)nullptr, 8192, 768, 768, 768);
}